// Round 9
// baseline (121.423 us; speedup 1.0000x reference)
//
#include <hip/hip_runtime.h>
#include <hip/hip_bf16.h>

#define BATCH    8192
#define NF       39      // num_fields
#define ED       64      // embed dim
#define RANK     32
#define KST      72      // Ef k-stride in halves (144 B): conflict-free b128 r/w (R6-measured class)
#define NFRAG    15      // 5 l-slices x 3 k-chunks
#define SPW      4       // samples per wave (depth-2 software pipeline)

typedef _Float16 half8  __attribute__((ext_vector_type(8)));
typedef float    f32x16 __attribute__((ext_vector_type(16)));

// ---- prep: 15 W A-fragments in per-lane MFMA layout ----
// wsW[(l*3+kc)*64 + lane] = half8 of W row j=lane&31, k = kc*16 + (lane>>5)*8 + e.
__global__ void prep_w(const float* __restrict__ W0,
                       const float* __restrict__ W1,
                       half8* __restrict__ wsW) {
    int d = blockIdx.x * 256 + threadIdx.x;
    if (d >= NFRAG * 64) return;
    int fid  = d >> 6;
    int lane = d & 63;
    int l = fid / 3, kc = fid % 3;
    int j = lane & 31, kh = lane >> 5;
    const float* base = (l < 2) ? (W0 + (l * RANK + j) * NF)
                                : (W1 + ((l - 2) * RANK + j) * NF);
    half8 h;
#pragma unroll
    for (int e = 0; e < 8; ++e) {
        int k = kc * 16 + kh * 8 + e;
        h[e] = (k < NF) ? (_Float16)base[k] : (_Float16)0.0f;
    }
    wsW[d] = h;
}

// ---- main: one wave = 4 samples, depth-2 gather pipeline ----
__global__ __launch_bounds__(256, 3) void tfm_kernel(
    const int*   __restrict__ x,        // (B, NF)
    const float* __restrict__ embed,    // (100000, ED) fp32
    const float* __restrict__ linw,     // (100000, 1)
    const float* __restrict__ lbias,    // (1,)
    const half8* __restrict__ wsW,      // [NFRAG][64]
    float*       __restrict__ out)      // (B,)
{
    __shared__ __align__(16) _Float16 Ws[NFRAG * 64 * 8];   // 15360 B
    __shared__ __align__(16) _Float16 Ef[4][ED][KST];       // 36864 B, wave-private slice

    const int t    = threadIdx.x;
    const int lane = t & 63;
    const int w    = t >> 6;
    const int s0   = (blockIdx.x * 4 + w) * SPW;

    const int j  = lane & 31;
    const int kh = lane >> 5;

    // ---- x vectors + linear gathers, all issued up front ----
    int xv[SPW];
#pragma unroll
    for (int si = 0; si < SPW; ++si)
        xv[si] = (lane < NF) ? x[(s0 + si) * NF + lane] : 0;
    float lv[SPW];
#pragma unroll
    for (int si = 0; si < SPW; ++si)
        lv[si] = (lane < NF) ? linw[xv[si]] : 0.0f;

    // ---- stage W frags into LDS (overlaps the prologue gathers) ----
    {
        const uint4* src = (const uint4*)wsW;
        uint4*       dst = (uint4*)Ws;
#pragma unroll
        for (int i = 0; i < NFRAG * 64 / 256; ++i)
            dst[i * 256 + t] = src[i * 256 + t];
        if (t < NFRAG * 64 - 768) dst[768 + t] = src[768 + t];
    }
    const float bias = lbias[0];

    // ---- gather slots: two 39-row batches in flight ----
    float r0[NF], r1[NF];

    auto issue = [&](int si, float* dst) {
#pragma unroll
        for (int k = 0; k < NF; ++k) {
            int xi = __builtin_amdgcn_readlane(xv[si], k);   // uniform -> SGPR base
            dst[k] = embed[(size_t)xi * ED + lane];          // coalesced 256B row
        }
    };
    auto pack = [&](const float* src) {
#pragma unroll
        for (int c6 = 0; c6 < 6; ++c6) {
            half8 hh;
#pragma unroll
            for (int e = 0; e < 8; ++e) {
                int k = c6 * 8 + e;
                hh[e] = (k < NF) ? (_Float16)src[k] : (_Float16)0.0f;
            }
            *(half8*)&Ef[w][lane][c6 * 8] = hh;
        }
    };
    const half8* Wf = (const half8*)Ws;
    auto compute_store = [&](float lvv, int sidx) {
        float ssum = lvv;
#pragma unroll
        for (int tile = 0; tile < 2; ++tile) {
            const int c = tile * 32 + j;
            half8 bf[3];
#pragma unroll
            for (int kc = 0; kc < 3; ++kc)
                bf[kc] = *(const half8*)&Ef[w][c][kc * 16 + kh * 8];
            {   // phase W0
                f32x16 a0, a1;
#pragma unroll
                for (int e = 0; e < 16; ++e) { a0[e] = 0.0f; a1[e] = 0.0f; }
#pragma unroll
                for (int kc = 0; kc < 3; ++kc) {
                    a0 = __builtin_amdgcn_mfma_f32_32x32x16_f16(Wf[(0 * 3 + kc) * 64 + lane], bf[kc], a0, 0, 0, 0);
                    a1 = __builtin_amdgcn_mfma_f32_32x32x16_f16(Wf[(1 * 3 + kc) * 64 + lane], bf[kc], a1, 0, 0, 0);
                }
#pragma unroll
                for (int e = 0; e < 16; ++e) ssum += a0[e] * a1[e];
            }
            {   // phase W1
                f32x16 c0, c1, c2;
#pragma unroll
                for (int e = 0; e < 16; ++e) { c0[e] = 0.0f; c1[e] = 0.0f; c2[e] = 0.0f; }
#pragma unroll
                for (int kc = 0; kc < 3; ++kc) {
                    c0 = __builtin_amdgcn_mfma_f32_32x32x16_f16(Wf[(2 * 3 + kc) * 64 + lane], bf[kc], c0, 0, 0, 0);
                    c1 = __builtin_amdgcn_mfma_f32_32x32x16_f16(Wf[(3 * 3 + kc) * 64 + lane], bf[kc], c1, 0, 0, 0);
                    c2 = __builtin_amdgcn_mfma_f32_32x32x16_f16(Wf[(4 * 3 + kc) * 64 + lane], bf[kc], c2, 0, 0, 0);
                }
#pragma unroll
                for (int e = 0; e < 16; ++e) ssum += c0[e] * c1[e] * c2[e];
            }
        }
#pragma unroll
        for (int off = 32; off > 0; off >>= 1) ssum += __shfl_down(ssum, off, 64);
        if (lane == 0) out[sidx] = ssum + bias;
    };

    // ---- depth-2 pipeline over 4 samples ----
    issue(0, r0);
    issue(1, r1);
    __syncthreads();                 // Ws visible; also drains prologue vmcnt (needed by pack anyway)

    pack(r0); issue(2, r0); compute_store(lv[0], s0 + 0);
    pack(r1); issue(3, r1); compute_store(lv[1], s0 + 1);
    pack(r0);               compute_store(lv[2], s0 + 2);
    pack(r1);               compute_store(lv[3], s0 + 3);
}

extern "C" void kernel_launch(void* const* d_in, const int* in_sizes, int n_in,
                              void* d_out, int out_size, void* d_ws, size_t ws_size,
                              hipStream_t stream) {
    const int*   x     = (const int*)  d_in[0];
    const float* embed = (const float*)d_in[1];
    const float* linw  = (const float*)d_in[2];
    const float* lbias = (const float*)d_in[3];
    const float* W0    = (const float*)d_in[4];
    const float* W1    = (const float*)d_in[5];
    float*       out   = (float*)d_out;
    half8*       wsW   = (half8*)d_ws;          // 15*64*16 B = 15360 B

    prep_w<<<(NFRAG * 64 + 255) / 256, 256, 0, stream>>>(W0, W1, wsW);
    // 512 blocks x 4 waves x 4 samples = 8192
    tfm_kernel<<<BATCH / (4 * SPW), 256, 0, stream>>>(x, embed, linw, lbias, wsW, out);
}

// Round 10
// 101.987 us; speedup vs baseline: 1.1906x; 1.1906x over previous
//
#include <hip/hip_runtime.h>
#include <hip/hip_bf16.h>

#define BATCH    8192
#define NF       39      // num_fields
#define ED       64      // embed dim
#define RANK     32
#define KST      56      // Ef k-stride in halves (112 B): lane->bank-group stride 7 (odd) -> conflict-free b128
#define NFRAG    15      // 5 l-slices x 3 k-chunks

typedef _Float16 half8  __attribute__((ext_vector_type(8)));
typedef float    f32x16 __attribute__((ext_vector_type(16)));

// ---- prep: 15 W A-fragments in per-lane MFMA layout ----
// wsW[(l*3+kc)*64 + lane] = half8 of W row j=lane&31, k = kc*16 + (lane>>5)*8 + e.
__global__ void prep_w(const float* __restrict__ W0,
                       const float* __restrict__ W1,
                       half8* __restrict__ wsW) {
    int d = blockIdx.x * 256 + threadIdx.x;
    if (d >= NFRAG * 64) return;
    int fid  = d >> 6;
    int lane = d & 63;
    int l = fid / 3, kc = fid % 3;
    int j = lane & 31, kh = lane >> 5;
    const float* base = (l < 2) ? (W0 + (l * RANK + j) * NF)
                                : (W1 + ((l - 2) * RANK + j) * NF);
    half8 h;
#pragma unroll
    for (int e = 0; e < 8; ++e) {
        int k = kc * 16 + kh * 8 + e;
        h[e] = (k < NF) ? (_Float16)base[k] : (_Float16)0.0f;
    }
    wsW[d] = h;
}

// ---- main: one wave = one sample (R6 skeleton); gathers bypass L1 via nt ----
__global__ __launch_bounds__(256, 3) void tfm_kernel(
    const int*   __restrict__ x,        // (B, NF)
    const float* __restrict__ embed,    // (100000, ED) fp32
    const float* __restrict__ linw,     // (100000, 1)
    const float* __restrict__ lbias,    // (1,)
    const half8* __restrict__ wsW,      // [NFRAG][64]
    float*       __restrict__ out)      // (B,)
{
    __shared__ __align__(16) _Float16 Ws[NFRAG * 64 * 8];   // 15360 B
    __shared__ __align__(16) _Float16 Ef[4][ED][KST];       // 28672 B, wave-private slice

    const int t    = threadIdx.x;
    const int lane = t & 63;
    const int w    = t >> 6;
    const int s    = blockIdx.x * 4 + w;     // one sample per wave

    const int j  = lane & 31;
    const int kh = lane >> 5;

    // ---- issue the gather chain first ----
    const int xi_v = (lane < NF) ? x[s * NF + lane] : 0;
    const float lv = (lane < NF) ? __builtin_nontemporal_load(linw + xi_v) : 0.0f;

    float r[NF];
#pragma unroll
    for (int k = 0; k < NF; ++k) {
        int xi = __builtin_amdgcn_readlane(xi_v, k);   // uniform -> SGPR base
        // nt: no L1 allocation -> misses queue in L2/TCC (deep), not L1 MSHRs
        r[k] = __builtin_nontemporal_load(embed + (size_t)xi * ED + lane);
    }

    // ---- stage W frags into LDS (independent loads, overlap the gather) ----
    {
        const uint4* src = (const uint4*)wsW;
        uint4*       dst = (uint4*)Ws;
#pragma unroll
        for (int i = 0; i < NFRAG * 64 / 256; ++i)      // 3 full passes of 256
            dst[i * 256 + t] = src[i * 256 + t];
        if (t < NFRAG * 64 - 768) dst[768 + t] = src[768 + t];
    }

    const float bias = lbias[0];

    // ---- pack f16 along k (lane = embed column), 6 x b128, wave-private ----
#pragma unroll
    for (int c6 = 0; c6 < 6; ++c6) {
        half8 hh;
#pragma unroll
        for (int e = 0; e < 8; ++e) {
            int k = c6 * 8 + e;
            hh[e] = (k < NF) ? (_Float16)r[k] : (_Float16)0.0f;
        }
        *(half8*)&Ef[w][lane][c6 * 8] = hh;
    }

    __syncthreads();   // Ws visible to all waves (Ef is wave-private)

    const half8* Wf = (const half8*)Ws;
    float ssum = lv;

#pragma unroll
    for (int tile = 0; tile < 2; ++tile) {
        const int c = tile * 32 + j;
        half8 bf[3];
#pragma unroll
        for (int kc = 0; kc < 3; ++kc)
            bf[kc] = *(const half8*)&Ef[w][c][kc * 16 + kh * 8];

        // phase W0: 2 accumulators, folded immediately
        {
            f32x16 a0, a1;
#pragma unroll
            for (int e = 0; e < 16; ++e) { a0[e] = 0.0f; a1[e] = 0.0f; }
#pragma unroll
            for (int kc = 0; kc < 3; ++kc) {
                a0 = __builtin_amdgcn_mfma_f32_32x32x16_f16(Wf[(0 * 3 + kc) * 64 + lane], bf[kc], a0, 0, 0, 0);
                a1 = __builtin_amdgcn_mfma_f32_32x32x16_f16(Wf[(1 * 3 + kc) * 64 + lane], bf[kc], a1, 0, 0, 0);
            }
#pragma unroll
            for (int e = 0; e < 16; ++e) ssum += a0[e] * a1[e];
        }
        // phase W1: 3 accumulators (reuses W0's registers)
        {
            f32x16 c0, c1, c2;
#pragma unroll
            for (int e = 0; e < 16; ++e) { c0[e] = 0.0f; c1[e] = 0.0f; c2[e] = 0.0f; }
#pragma unroll
            for (int kc = 0; kc < 3; ++kc) {
                c0 = __builtin_amdgcn_mfma_f32_32x32x16_f16(Wf[(2 * 3 + kc) * 64 + lane], bf[kc], c0, 0, 0, 0);
                c1 = __builtin_amdgcn_mfma_f32_32x32x16_f16(Wf[(3 * 3 + kc) * 64 + lane], bf[kc], c1, 0, 0, 0);
                c2 = __builtin_amdgcn_mfma_f32_32x32x16_f16(Wf[(4 * 3 + kc) * 64 + lane], bf[kc], c2, 0, 0, 0);
            }
#pragma unroll
            for (int e = 0; e < 16; ++e) ssum += c0[e] * c1[e] * c2[e];
        }
    }

    // ---- 64-lane reduce, lane 0 writes ----
#pragma unroll
    for (int off = 32; off > 0; off >>= 1) ssum += __shfl_down(ssum, off, 64);
    if (lane == 0) out[s] = ssum + bias;
}

extern "C" void kernel_launch(void* const* d_in, const int* in_sizes, int n_in,
                              void* d_out, int out_size, void* d_ws, size_t ws_size,
                              hipStream_t stream) {
    const int*   x     = (const int*)  d_in[0];
    const float* embed = (const float*)d_in[1];
    const float* linw  = (const float*)d_in[2];
    const float* lbias = (const float*)d_in[3];
    const float* W0    = (const float*)d_in[4];
    const float* W1    = (const float*)d_in[5];
    float*       out   = (float*)d_out;
    half8*       wsW   = (half8*)d_ws;          // 15*64*16 B = 15360 B

    prep_w<<<(NFRAG * 64 + 255) / 256, 256, 0, stream>>>(W0, W1, wsW);
    // 2048 blocks x 4 waves x 1 sample = 8192
    tfm_kernel<<<BATCH / 4, 256, 0, stream>>>(x, embed, linw, lbias, wsW, out);
}